// Round 2
// baseline (660.085 us; speedup 1.0000x reference)
//
#include <hip/hip_runtime.h>

#define B_TOT 16384
#define HD 256
#define ID 128
#define BT 64            // two 32-row sub-tiles per block, pipelined in-wave
#define NSTEP 8
#define YP 264           // y/u LDS pitch (f16)
#define XP 136
#define HP 260           // master-h LDS pitch (f32): 260%32=4 -> max 4-way conflict

typedef float    f32x4  __attribute__((ext_vector_type(4)));
typedef float    f32x16 __attribute__((ext_vector_type(16)));
typedef _Float16 f16x8  __attribute__((ext_vector_type(8)));
typedef _Float16 f16x4  __attribute__((ext_vector_type(4)));
typedef _Float16 f16x2  __attribute__((ext_vector_type(2)));

__device__ __forceinline__ float fast_rcp(float x){ return __builtin_amdgcn_rcpf(x); }
__device__ __forceinline__ float fast_exp2(float x){ return __builtin_amdgcn_exp2f(x); }
__device__ __forceinline__ float fast_tanh(float x){
  return 1.0f - 2.0f*fast_rcp(1.0f + fast_exp2(x*2.8853900817779268f));
}
__device__ __forceinline__ float fast_sigmoid(float x){
  return fast_rcp(1.0f + fast_exp2(x*-1.4426950408889634f));
}

__global__ void cvt_f32_f16(const float* __restrict__ src, _Float16* __restrict__ dst, int n4){
  int i = blockIdx.x*256 + threadIdx.x;
  if (i < n4){
    float4 v = ((const float4*)src)[i];
    f16x4 t = {(_Float16)v.x, (_Float16)v.y, (_Float16)v.z, (_Float16)v.w};
    *(f16x4*)(dst + (size_t)i*4) = t;
  }
}

// acc element r: feat = 32*wv + 8*(r>>2) + 4*hh + (r&3), batch = l31
#define KPF(K,i) ((float)K[i][pk][hw])

// Dormand-Prince stage-argument expressions (h = hv[r3], kd = current dt*k)
#define YX0(K) (hv[r3] + 0.2f*kd)
#define YX1(K) (hv[r3] + 0.075f*KPF(K,0) + 0.225f*kd)
#define YX2(K) (hv[r3] + (44.0f/45.0f)*KPF(K,0) + (-56.0f/15.0f)*KPF(K,1) + (32.0f/9.0f)*kd)
#define YX3(K) (hv[r3] + (19372.0f/6561.0f)*KPF(K,0) + (-25360.0f/2187.0f)*KPF(K,1) \
                        + (64448.0f/6561.0f)*KPF(K,2) + (-212.0f/729.0f)*kd)
#define YX4(K) (hv[r3] + (9017.0f/3168.0f)*KPF(K,0) + (-355.0f/33.0f)*KPF(K,1) \
                        + (46732.0f/5247.0f)*KPF(K,2) + (49.0f/176.0f)*KPF(K,3) \
                        + (-5103.0f/18656.0f)*kd)
#define YX5(K) (hv[r3] + (35.0f/384.0f)*KPF(K,0) + (500.0f/1113.0f)*KPF(K,2) \
                        + (125.0f/192.0f)*KPF(K,3) + (-2187.0f/6784.0f)*KPF(K,4) \
                        + (11.0f/84.0f)*kd)

// k-epilogue: consume ACC, store k (SIDX<5), write stage arg (f16) to YB;
// SIDX==5 also updates master h (f32 in LDS).
#define EPI2(ACC, YB, HS, K, DTV, SIDX, YXM)                               \
  { _Pragma("unroll")                                                      \
    for (int g2 = 0; g2 < 4; ++g2){                                        \
      f32x4 hv = *(const f32x4*)(HS + hoff + 8*g2);                        \
      f32x4 bv = *(const f32x4*)(b2l + cb + 8*g2);                         \
      f16x4 yv; f32x4 hnv;                                                 \
      _Pragma("unroll")                                                    \
      for (int r3 = 0; r3 < 4; ++r3){                                      \
        const int r = g2*4 + r3; const int pk = r>>1; const int hw = r&1;  \
        float kd = DTV*(ACC[r] + bv[r3]);                                  \
        if ((SIDX) < 5) K[(SIDX)<5?(SIDX):0][pk][hw] = (_Float16)kd;       \
        float yn = YXM(K);                                                 \
        hnv[r3] = yn;                                                      \
        yv[r3] = (_Float16)yn;                                             \
      }                                                                    \
      if ((SIDX) == 5) *(f32x4*)(HS + hoff + 8*g2) = hnv;                  \
      *(f16x4*)(YB + yoff + 8*g2) = yv;                                    \
    }                                                                      \
  }

// tanh epilogue: u = tanh(ACC + b1) -> YB (buffer switches role y->u)
#define EPI1(ACC, YB)                                                      \
  { _Pragma("unroll")                                                      \
    for (int g2 = 0; g2 < 4; ++g2){                                        \
      f32x4 bv = *(const f32x4*)(b1l + cb + 8*g2);                         \
      f16x4 uv;                                                            \
      _Pragma("unroll")                                                    \
      for (int r3 = 0; r3 < 4; ++r3)                                       \
        uv[r3] = (_Float16)fast_tanh(ACC[g2*4+r3] + bv[r3]);               \
      *(f16x4*)(YB + yoff + 8*g2) = uv;                                    \
    }                                                                      \
  }

// segments B,C,D of stage S (seg A is stage-specific: carries prev EPI2 of B)
#define SEGBCD(S)                                                          \
  aB = gemm16(W1f, ybB);  EPI1(aA, ybA);  __syncthreads();                 \
  aA = gemm16(W2f, ybA);  EPI1(aB, ybB);  __syncthreads();                 \
  aB = gemm16(W2f, ybB);  EPI2(aA, ybA, hslA, kpkA, dtvA, S, YX##S);       \
  __syncthreads();

#define STAGE4(S, SP)                                                      \
  aA = gemm16(W1f, ybA);                                                   \
  EPI2(aB, ybB, hslB, kpkB, dtvB, SP, YX##SP);                             \
  __syncthreads();                                                         \
  SEGBCD(S)

__global__ __launch_bounds__(512, 2)
void ode_lstm(const float* __restrict__ inputs, const float* __restrict__ h0,
              const float* __restrict__ c0,     const float* __restrict__ ts,
              const float* __restrict__ b_ih,   const float* __restrict__ b_hh,
              const float* __restrict__ b1,     const float* __restrict__ b2,
              const _Float16* __restrict__ W1h, const _Float16* __restrict__ W2h,
              const _Float16* __restrict__ Wihh,const _Float16* __restrict__ Whhh,
              float* __restrict__ out)
{
  __shared__ __align__(16) _Float16 ybA[32*YP], ybB[32*YP];  // y/u role-alternating
  __shared__ __align__(16) float    hslA[32*HP], hslB[32*HP];// master h (f32)
  __shared__ __align__(16) float    b1l[HD], b2l[HD], bsl[4*HD];
  __shared__ float dtl[BT];

  const int tid  = threadIdx.x;
  const int wv   = tid >> 6;
  const int lane = tid & 63;
  const int l31  = lane & 31;
  const int hh   = lane >> 5;
  const int row0 = blockIdx.x * BT;
  const int cb   = wv*32 + hh*4;
  const int yoff = l31*YP + cb;     // f16-elem offset (y/u buffers)
  const int hoff = l31*HP + cb;     // f32-elem offset (h buffers)

  if (tid < HD){ b1l[tid] = b1[tid]; b2l[tid] = b2[tid]; }
  bsl[tid]       = b_ih[tid]       + b_hh[tid];
  bsl[tid + 512] = b_ih[tid + 512] + b_hh[tid + 512];
  if (tid < BT) dtl[tid] = ts[row0 + tid] * (1.0f/NSTEP);

  // W1, W2 strips in VGPRs for the whole RK45 loop
  f16x8 W1f[16], W2f[16];
  {
    const _Float16* w1p = W1h + (size_t)(wv*32 + l31)*HD + hh*8;
    const _Float16* w2p = W2h + (size_t)(wv*32 + l31)*HD + hh*8;
    #pragma unroll
    for (int kt = 0; kt < 16; ++kt){
      W1f[kt] = *(const f16x8*)(w1p + kt*16);
      W2f[kt] = *(const f16x8*)(w2p + kt*16);
    }
  }

  // h0 -> h LDS (f32) + y buffers (f16) for both sub-tiles
  #pragma unroll
  for (int g2 = 0; g2 < 4; ++g2){
    f32x4 ha = *(const f32x4*)(h0 + (size_t)(row0 + l31)*HD + cb + 8*g2);
    f32x4 hb = *(const f32x4*)(h0 + (size_t)(row0 + 32 + l31)*HD + cb + 8*g2);
    *(f32x4*)(hslA + hoff + 8*g2) = ha;
    *(f32x4*)(hslB + hoff + 8*g2) = hb;
    f16x4 ta = {(_Float16)ha[0],(_Float16)ha[1],(_Float16)ha[2],(_Float16)ha[3]};
    f16x4 tb = {(_Float16)hb[0],(_Float16)hb[1],(_Float16)hb[2],(_Float16)hb[3]};
    *(f16x4*)(ybA + yoff + 8*g2) = ta;
    *(f16x4*)(ybB + yoff + 8*g2) = tb;
  }
  __syncthreads();
  const float dtvA = dtl[l31], dtvB = dtl[32 + l31];

  auto gemm16 = [&](const f16x8 (&Wf)[16], const _Float16* __restrict__ act)->f32x16{
    f32x16 a = {};
    const _Float16* bp = act + l31*YP + hh*8;
    #pragma unroll
    for (int kt = 0; kt < 16; ++kt){
      f16x8 Bf = *(const f16x8*)(bp + kt*16);
      a = __builtin_amdgcn_mfma_f32_32x32x16_f16(Wf[kt], Bf, a, 0, 0, 0);
    }
    return a;
  };

  // ================= RK45, two sub-tiles software-pipelined =================
  f32x16 aA, aB;
  f16x2 kpkA[5][8], kpkB[5][8];

  #pragma unroll 1
  for (int step = 0; step < NSTEP; ++step){
    // stage 0, segment A: gemm1A + (pending EPI2 of B's stage 5 from prev step)
    aA = gemm16(W1f, ybA);
    if (step > 0) { EPI2(aB, ybB, hslB, kpkB, dtvB, 5, YX5); }
    __syncthreads();
    SEGBCD(0)
    STAGE4(1, 0)
    STAGE4(2, 1)
    STAGE4(3, 2)
    STAGE4(4, 3)
    STAGE4(5, 4)
  }
  // flush: B's final stage-5 epilogue (h update + y = h)
  { EPI2(aB, ybB, hslB, kpkB, dtvB, 5, YX5); }
  __syncthreads();

  // ================= two weight-shared LSTM cells, per sub-tile =============
  // h LDS region is dead now (final h lives as f16 in ybA/ybB) -> reuse for x and h1.
  _Float16* xA  = (_Float16*)hslA;
  _Float16* xB  = (_Float16*)hslB;
  _Float16* h1A = ((_Float16*)hslA) + 32*XP;
  _Float16* h1B = ((_Float16*)hslB) + 32*XP;

  #pragma unroll
  for (int it = 0; it < 4; ++it){
    int idx = tid + it*512;                 // 64 rows * 32 float4
    int r = idx >> 5, c4 = idx & 31;
    float4 v = ((const float4*)inputs)[(size_t)(row0 + r)*(ID/4) + c4];
    f16x4 t = {(_Float16)v.x, (_Float16)v.y, (_Float16)v.z, (_Float16)v.w};
    _Float16* xd = (r < 32) ? xA : xB;
    *(f16x4*)(xd + (r & 31)*XP + c4*4) = t;
  }
  __syncthreads();

  #pragma unroll 1
  for (int sb = 0; sb < 2; ++sb){
    const _Float16* xs  = sb ? xB  : xA;
    const _Float16* hod = sb ? ybB : ybA;
    _Float16*       h1  = sb ? h1B : h1A;
    const int rbase = row0 + sb*32;

    // x-part of gates (shared by both cells)
    f32x16 agx[4] = {};
    {
      const _Float16* bp = xs + l31*XP + hh*8;
      #pragma unroll 2
      for (int kt = 0; kt < 8; ++kt){
        f16x8 Bf = *(const f16x8*)(bp + kt*16);
        #pragma unroll
        for (int g = 0; g < 4; ++g){
          f16x8 Af = *(const f16x8*)(Wihh + (size_t)(g*HD + wv*32 + l31)*ID + kt*16 + hh*8);
          agx[g] = __builtin_amdgcn_mfma_f32_32x32x16_f16(Af, Bf, agx[g], 0, 0, 0);
        }
      }
    }
    f32x4 c4v[4];
    #pragma unroll
    for (int g2 = 0; g2 < 4; ++g2)
      c4v[g2] = *(const f32x4*)(c0 + (size_t)(rbase + l31)*HD + cb + 8*g2);

    #pragma unroll 1
    for (int cell = 0; cell < 2; ++cell){
      f32x16 ag[4];
      #pragma unroll
      for (int g = 0; g < 4; ++g) ag[g] = agx[g];
      const _Float16* hb = (cell == 0) ? hod : h1;
      const _Float16* bp = hb + l31*YP + hh*8;
      #pragma unroll 2
      for (int kt = 0; kt < 16; ++kt){
        f16x8 Bf = *(const f16x8*)(bp + kt*16);
        #pragma unroll
        for (int g = 0; g < 4; ++g){
          f16x8 Af = *(const f16x8*)(Whhh + (size_t)(g*HD + wv*32 + l31)*HD + kt*16 + hh*8);
          ag[g] = __builtin_amdgcn_mfma_f32_32x32x16_f16(Af, Bf, ag[g], 0, 0, 0);
        }
      }
      #pragma unroll
      for (int g2 = 0; g2 < 4; ++g2){
        f32x4 bi = *(const f32x4*)(bsl + 0*HD + cb + 8*g2);
        f32x4 bf = *(const f32x4*)(bsl + 1*HD + cb + 8*g2);
        f32x4 bg = *(const f32x4*)(bsl + 2*HD + cb + 8*g2);
        f32x4 bo = *(const f32x4*)(bsl + 3*HD + cb + 8*g2);
        f16x4 hv16; f32x4 ho, co;
        #pragma unroll
        for (int r3 = 0; r3 < 4; ++r3){
          const int r = g2*4 + r3;
          float iv = fast_sigmoid(ag[0][r] + bi[r3]);
          float fv = fast_sigmoid(ag[1][r] + bf[r3]);
          float gv = fast_tanh   (ag[2][r] + bg[r3]);
          float ov = fast_sigmoid(ag[3][r] + bo[r3]);
          float cn = fv*c4v[g2][r3] + iv*gv;
          c4v[g2][r3] = cn;
          float hn = ov*fast_tanh(cn);
          hv16[r3] = (_Float16)hn; ho[r3] = hn; co[r3] = cn;
        }
        if (cell == 0){
          *(f16x4*)(h1 + yoff + 8*g2) = hv16;        // h1 -> cell2 input
        } else {
          size_t o = (size_t)(rbase + l31)*HD + cb + 8*g2;
          *(f32x4*)(out + o) = ho;                   // h2
          *(f32x4*)(out + (size_t)B_TOT*HD + o) = co;// c2
        }
      }
      if (cell == 0) __syncthreads();
    }
  }
}

extern "C" void kernel_launch(void* const* d_in, const int* in_sizes, int n_in,
                              void* d_out, int out_size, void* d_ws, size_t ws_size,
                              hipStream_t stream) {
  (void)in_sizes; (void)n_in; (void)out_size; (void)ws_size;
  const float* inputs = (const float*)d_in[0];
  const float* h0     = (const float*)d_in[1];
  const float* c0     = (const float*)d_in[2];
  const float* ts     = (const float*)d_in[3];
  const float* W_ih   = (const float*)d_in[4];
  const float* W_hh   = (const float*)d_in[5];
  const float* b_ih   = (const float*)d_in[6];
  const float* b_hh   = (const float*)d_in[7];
  const float* W1     = (const float*)d_in[8];
  const float* b1     = (const float*)d_in[9];
  const float* W2     = (const float*)d_in[10];
  const float* b2     = (const float*)d_in[11];
  float* out = (float*)d_out;

  _Float16* wsh  = (_Float16*)d_ws;
  _Float16* W1h  = wsh;             // 65536
  _Float16* W2h  = wsh + 65536;     // 65536
  _Float16* Wihh = wsh + 131072;    // 131072
  _Float16* Whhh = wsh + 262144;    // 262144  (total 1 MB)

  cvt_f32_f16<<<64,  256, 0, stream>>>(W1,   W1h,  16384);
  cvt_f32_f16<<<64,  256, 0, stream>>>(W2,   W2h,  16384);
  cvt_f32_f16<<<128, 256, 0, stream>>>(W_ih, Wihh, 32768);
  cvt_f32_f16<<<256, 256, 0, stream>>>(W_hh, Whhh, 65536);

  ode_lstm<<<B_TOT/BT, 512, 0, stream>>>(inputs, h0, c0, ts, b_ih, b_hh, b1, b2,
                                         W1h, W2h, Wihh, Whhh, out);
}

// Round 3
// 639.967 us; speedup vs baseline: 1.0314x; 1.0314x over previous
//
#include <hip/hip_runtime.h>

#define B_TOT 16384
#define HD 256
#define ID 128
#define BT 64            // two 32-row sub-tiles per block, pipelined in-wave
#define NSTEP 8
#define YP 264           // y/u LDS pitch (f16)
#define XP 136
#define HP 260           // master-h LDS pitch (f32): 260%32=4 -> max 4-way conflict

typedef float    f32x4  __attribute__((ext_vector_type(4)));
typedef float    f32x16 __attribute__((ext_vector_type(16)));
typedef _Float16 f16x8  __attribute__((ext_vector_type(8)));
typedef _Float16 f16x4  __attribute__((ext_vector_type(4)));
typedef _Float16 f16x2  __attribute__((ext_vector_type(2)));

__device__ __forceinline__ float fast_rcp(float x){ return __builtin_amdgcn_rcpf(x); }
__device__ __forceinline__ float fast_exp2(float x){ return __builtin_amdgcn_exp2f(x); }
__device__ __forceinline__ float fast_tanh(float x){
  return 1.0f - 2.0f*fast_rcp(1.0f + fast_exp2(x*2.8853900817779268f));
}
__device__ __forceinline__ float fast_sigmoid(float x){
  return fast_rcp(1.0f + fast_exp2(x*-1.4426950408889634f));
}

__global__ void cvt_f32_f16(const float* __restrict__ src, _Float16* __restrict__ dst, int n4){
  int i = blockIdx.x*256 + threadIdx.x;
  if (i < n4){
    float4 v = ((const float4*)src)[i];
    f16x4 t = {(_Float16)v.x, (_Float16)v.y, (_Float16)v.z, (_Float16)v.w};
    *(f16x4*)(dst + (size_t)i*4) = t;
  }
}

// acc element r: feat = 32*wv + 8*(r>>2) + 4*hh + (r&3), batch = l31
// kpk slot map: k1->0, k2->1, k3->2, k4->3, k5->1 (k2 dead after YX4 is formed)
#define KPF(K,i) ((float)K[i][pk][hw])
#define SLOT(S) ((S) < 4 ? (S) : 1)

// Dormand-Prince stage-argument expressions (h = hv[r3], kd = current dt*k)
#define YX0(K) (hv[r3] + 0.2f*kd)
#define YX1(K) (hv[r3] + 0.075f*KPF(K,0) + 0.225f*kd)
#define YX2(K) (hv[r3] + (44.0f/45.0f)*KPF(K,0) + (-56.0f/15.0f)*KPF(K,1) + (32.0f/9.0f)*kd)
#define YX3(K) (hv[r3] + (19372.0f/6561.0f)*KPF(K,0) + (-25360.0f/2187.0f)*KPF(K,1) \
                        + (64448.0f/6561.0f)*KPF(K,2) + (-212.0f/729.0f)*kd)
#define YX4(K) (hv[r3] + (9017.0f/3168.0f)*KPF(K,0) + (-355.0f/33.0f)*KPF(K,1) \
                        + (46732.0f/5247.0f)*KPF(K,2) + (49.0f/176.0f)*KPF(K,3) \
                        + (-5103.0f/18656.0f)*kd)
// k5 lives in slot 1
#define YX5(K) (hv[r3] + (35.0f/384.0f)*KPF(K,0) + (500.0f/1113.0f)*KPF(K,2) \
                        + (125.0f/192.0f)*KPF(K,3) + (-2187.0f/6784.0f)*KPF(K,1) \
                        + (11.0f/84.0f)*kd)

// k-epilogue: ACC already contains b2 (bias-init). Compute yn BEFORE storing kd
// (stage 4 reads slot 1 = k2 in YX4, then overwrites it with k5).
#define EPI2(ACC, YB, HS, K, DTV, SIDX, YXM)                               \
  { _Pragma("unroll")                                                      \
    for (int g2 = 0; g2 < 4; ++g2){                                        \
      f32x4 hv = *(const f32x4*)(HS + hoff + 8*g2);                        \
      f16x4 yv; f32x4 hnv;                                                 \
      _Pragma("unroll")                                                    \
      for (int r3 = 0; r3 < 4; ++r3){                                      \
        const int r = g2*4 + r3; const int pk = r>>1; const int hw = r&1;  \
        float kd = DTV*ACC[r];                                             \
        float yn = YXM(K);                                                 \
        if ((SIDX) < 5) K[SLOT(SIDX)][pk][hw] = (_Float16)kd;              \
        hnv[r3] = yn;                                                      \
        yv[r3] = (_Float16)yn;                                             \
      }                                                                    \
      if ((SIDX) == 5) *(f32x4*)(HS + hoff + 8*g2) = hnv;                  \
      *(f16x4*)(YB + yoff + 8*g2) = yv;                                    \
    }                                                                      \
  }

// tanh epilogue: ACC already contains b1. u = tanh(ACC) -> YB
#define EPI1(ACC, YB)                                                      \
  { _Pragma("unroll")                                                      \
    for (int g2 = 0; g2 < 4; ++g2){                                        \
      f16x4 uv;                                                            \
      _Pragma("unroll")                                                    \
      for (int r3 = 0; r3 < 4; ++r3)                                       \
        uv[r3] = (_Float16)fast_tanh(ACC[g2*4+r3]);                        \
      *(f16x4*)(YB + yoff + 8*g2) = uv;                                    \
    }                                                                      \
  }

// segments B,C,D of stage S (seg A is stage-specific: carries prev EPI2 of B)
#define SEGBCD(S)                                                          \
  aB = gemm16(W1f, ybB, b1l);  EPI1(aA, ybA);  __syncthreads();            \
  aA = gemm16(W2f, ybA, b2l);  EPI1(aB, ybB);  __syncthreads();            \
  aB = gemm16(W2f, ybB, b2l);  EPI2(aA, ybA, hslA, kpkA, dtvA, S, YX##S);  \
  __syncthreads();

#define STAGE4(S, SP)                                                      \
  aA = gemm16(W1f, ybA, b1l);                                              \
  EPI2(aB, ybB, hslB, kpkB, dtvB, SP, YX##SP);                             \
  __syncthreads();                                                         \
  SEGBCD(S)

__global__ __launch_bounds__(512, 2)
void ode_lstm(const float* __restrict__ inputs, const float* __restrict__ h0,
              const float* __restrict__ c0,     const float* __restrict__ ts,
              const float* __restrict__ b_ih,   const float* __restrict__ b_hh,
              const float* __restrict__ b1,     const float* __restrict__ b2,
              const _Float16* __restrict__ W1h, const _Float16* __restrict__ W2h,
              const _Float16* __restrict__ Wihh,const _Float16* __restrict__ Whhh,
              float* __restrict__ out)
{
  __shared__ __align__(16) _Float16 ybA[32*YP], ybB[32*YP];  // y/u role-alternating
  __shared__ __align__(16) float    hslA[32*HP], hslB[32*HP];// master h (f32)
  __shared__ __align__(16) float    b1l[HD], b2l[HD], bsl[4*HD];
  __shared__ float dtl[BT];

  const int tid  = threadIdx.x;
  const int wv   = tid >> 6;
  const int lane = tid & 63;
  const int l31  = lane & 31;
  const int hh   = lane >> 5;
  const int row0 = blockIdx.x * BT;
  const int cb   = wv*32 + hh*4;
  const int yoff = l31*YP + cb;     // f16-elem offset (y/u buffers)
  const int hoff = l31*HP + cb;     // f32-elem offset (h buffers)

  if (tid < HD){ b1l[tid] = b1[tid]; b2l[tid] = b2[tid]; }
  bsl[tid]       = b_ih[tid]       + b_hh[tid];
  bsl[tid + 512] = b_ih[tid + 512] + b_hh[tid + 512];
  if (tid < BT) dtl[tid] = ts[row0 + tid] * (1.0f/NSTEP);

  // W1, W2 strips in VGPRs for the whole RK45 loop (128 regs; hard floor)
  f16x8 W1f[16], W2f[16];
  {
    const _Float16* w1p = W1h + (size_t)(wv*32 + l31)*HD + hh*8;
    const _Float16* w2p = W2h + (size_t)(wv*32 + l31)*HD + hh*8;
    #pragma unroll
    for (int kt = 0; kt < 16; ++kt){
      W1f[kt] = *(const f16x8*)(w1p + kt*16);
      W2f[kt] = *(const f16x8*)(w2p + kt*16);
    }
  }

  // h0 -> h LDS (f32) + y buffers (f16) for both sub-tiles
  #pragma unroll
  for (int g2 = 0; g2 < 4; ++g2){
    f32x4 ha = *(const f32x4*)(h0 + (size_t)(row0 + l31)*HD + cb + 8*g2);
    f32x4 hb = *(const f32x4*)(h0 + (size_t)(row0 + 32 + l31)*HD + cb + 8*g2);
    *(f32x4*)(hslA + hoff + 8*g2) = ha;
    *(f32x4*)(hslB + hoff + 8*g2) = hb;
    f16x4 ta = {(_Float16)ha[0],(_Float16)ha[1],(_Float16)ha[2],(_Float16)ha[3]};
    f16x4 tb = {(_Float16)hb[0],(_Float16)hb[1],(_Float16)hb[2],(_Float16)hb[3]};
    *(f16x4*)(ybA + yoff + 8*g2) = ta;
    *(f16x4*)(ybB + yoff + 8*g2) = tb;
  }
  __syncthreads();
  const float dtvA = dtl[l31], dtvB = dtl[32 + l31];

  // GEMM with bias-init C (saves epilogue adds + bv temps)
  auto gemm16 = [&](const f16x8 (&Wf)[16], const _Float16* __restrict__ act,
                    const float* __restrict__ bL)->f32x16{
    f32x16 a;
    #pragma unroll
    for (int g2 = 0; g2 < 4; ++g2){
      f32x4 bv = *(const f32x4*)(bL + cb + 8*g2);
      a[g2*4+0] = bv[0]; a[g2*4+1] = bv[1]; a[g2*4+2] = bv[2]; a[g2*4+3] = bv[3];
    }
    const _Float16* bp = act + l31*YP + hh*8;
    #pragma unroll
    for (int kt = 0; kt < 16; ++kt){
      f16x8 Bf = *(const f16x8*)(bp + kt*16);
      a = __builtin_amdgcn_mfma_f32_32x32x16_f16(Wf[kt], Bf, a, 0, 0, 0);
    }
    return a;
  };

  // ================= RK45, two sub-tiles software-pipelined =================
  f32x16 aA, aB;
  f16x2 kpkA[4][8], kpkB[4][8];   // 32 regs each (k5 shares k2's slot)

  #pragma unroll 1
  for (int step = 0; step < NSTEP; ++step){
    // stage 0, segment A: gemm1A + (pending EPI2 of B's stage 5 from prev step)
    aA = gemm16(W1f, ybA, b1l);
    if (step > 0) { EPI2(aB, ybB, hslB, kpkB, dtvB, 5, YX5); }
    __syncthreads();
    SEGBCD(0)
    STAGE4(1, 0)
    STAGE4(2, 1)
    STAGE4(3, 2)
    STAGE4(4, 3)
    STAGE4(5, 4)
  }
  // flush: B's final stage-5 epilogue (h update + y = h)
  { EPI2(aB, ybB, hslB, kpkB, dtvB, 5, YX5); }
  __syncthreads();

  // ================= two weight-shared LSTM cells, per sub-tile =============
  // h LDS region is dead now (final h lives as f16 in ybA/ybB) -> reuse for x and h1.
  _Float16* xA  = (_Float16*)hslA;
  _Float16* xB  = (_Float16*)hslB;
  _Float16* h1A = ((_Float16*)hslA) + 32*XP;
  _Float16* h1B = ((_Float16*)hslB) + 32*XP;

  #pragma unroll
  for (int it = 0; it < 4; ++it){
    int idx = tid + it*512;                 // 64 rows * 32 float4
    int r = idx >> 5, c4 = idx & 31;
    float4 v = ((const float4*)inputs)[(size_t)(row0 + r)*(ID/4) + c4];
    f16x4 t = {(_Float16)v.x, (_Float16)v.y, (_Float16)v.z, (_Float16)v.w};
    _Float16* xd = (r < 32) ? xA : xB;
    *(f16x4*)(xd + (r & 31)*XP + c4*4) = t;
  }
  __syncthreads();

  #pragma unroll 1
  for (int sb = 0; sb < 2; ++sb){
    const _Float16* xs  = sb ? xB  : xA;
    const _Float16* hod = sb ? ybB : ybA;
    _Float16*       h1  = sb ? h1B : h1A;
    const int rbase = row0 + sb*32;

    // x-part of gates (shared by both cells), bias-init with b_ih+b_hh
    f32x16 agx[4];
    #pragma unroll
    for (int g = 0; g < 4; ++g){
      #pragma unroll
      for (int g2 = 0; g2 < 4; ++g2){
        f32x4 bv = *(const f32x4*)(bsl + g*HD + cb + 8*g2);
        agx[g][g2*4+0] = bv[0]; agx[g][g2*4+1] = bv[1];
        agx[g][g2*4+2] = bv[2]; agx[g][g2*4+3] = bv[3];
      }
    }
    {
      const _Float16* bp = xs + l31*XP + hh*8;
      #pragma unroll 2
      for (int kt = 0; kt < 8; ++kt){
        f16x8 Bf = *(const f16x8*)(bp + kt*16);
        #pragma unroll
        for (int g = 0; g < 4; ++g){
          f16x8 Af = *(const f16x8*)(Wihh + (size_t)(g*HD + wv*32 + l31)*ID + kt*16 + hh*8);
          agx[g] = __builtin_amdgcn_mfma_f32_32x32x16_f16(Af, Bf, agx[g], 0, 0, 0);
        }
      }
    }
    f32x4 c4v[4];
    #pragma unroll
    for (int g2 = 0; g2 < 4; ++g2)
      c4v[g2] = *(const f32x4*)(c0 + (size_t)(rbase + l31)*HD + cb + 8*g2);

    #pragma unroll 1
    for (int cell = 0; cell < 2; ++cell){
      f32x16 ag[4];
      #pragma unroll
      for (int g = 0; g < 4; ++g) ag[g] = agx[g];
      const _Float16* hb = (cell == 0) ? hod : h1;
      const _Float16* bp = hb + l31*YP + hh*8;
      #pragma unroll 2
      for (int kt = 0; kt < 16; ++kt){
        f16x8 Bf = *(const f16x8*)(bp + kt*16);
        #pragma unroll
        for (int g = 0; g < 4; ++g){
          f16x8 Af = *(const f16x8*)(Whhh + (size_t)(g*HD + wv*32 + l31)*HD + kt*16 + hh*8);
          ag[g] = __builtin_amdgcn_mfma_f32_32x32x16_f16(Af, Bf, ag[g], 0, 0, 0);
        }
      }
      #pragma unroll
      for (int g2 = 0; g2 < 4; ++g2){
        f16x4 hv16; f32x4 ho, co;
        #pragma unroll
        for (int r3 = 0; r3 < 4; ++r3){
          const int r = g2*4 + r3;
          float iv = fast_sigmoid(ag[0][r]);
          float fv = fast_sigmoid(ag[1][r]);
          float gv = fast_tanh   (ag[2][r]);
          float ov = fast_sigmoid(ag[3][r]);
          float cn = fv*c4v[g2][r3] + iv*gv;
          c4v[g2][r3] = cn;
          float hn = ov*fast_tanh(cn);
          hv16[r3] = (_Float16)hn; ho[r3] = hn; co[r3] = cn;
        }
        if (cell == 0){
          *(f16x4*)(h1 + yoff + 8*g2) = hv16;        // h1 -> cell2 input
        } else {
          size_t o = (size_t)(rbase + l31)*HD + cb + 8*g2;
          *(f32x4*)(out + o) = ho;                   // h2
          *(f32x4*)(out + (size_t)B_TOT*HD + o) = co;// c2
        }
      }
      if (cell == 0) __syncthreads();
    }
  }
}

extern "C" void kernel_launch(void* const* d_in, const int* in_sizes, int n_in,
                              void* d_out, int out_size, void* d_ws, size_t ws_size,
                              hipStream_t stream) {
  (void)in_sizes; (void)n_in; (void)out_size; (void)ws_size;
  const float* inputs = (const float*)d_in[0];
  const float* h0     = (const float*)d_in[1];
  const float* c0     = (const float*)d_in[2];
  const float* ts     = (const float*)d_in[3];
  const float* W_ih   = (const float*)d_in[4];
  const float* W_hh   = (const float*)d_in[5];
  const float* b_ih   = (const float*)d_in[6];
  const float* b_hh   = (const float*)d_in[7];
  const float* W1     = (const float*)d_in[8];
  const float* b1     = (const float*)d_in[9];
  const float* W2     = (const float*)d_in[10];
  const float* b2     = (const float*)d_in[11];
  float* out = (float*)d_out;

  _Float16* wsh  = (_Float16*)d_ws;
  _Float16* W1h  = wsh;             // 65536
  _Float16* W2h  = wsh + 65536;     // 65536
  _Float16* Wihh = wsh + 131072;    // 131072
  _Float16* Whhh = wsh + 262144;    // 262144  (total 1 MB)

  cvt_f32_f16<<<64,  256, 0, stream>>>(W1,   W1h,  16384);
  cvt_f32_f16<<<64,  256, 0, stream>>>(W2,   W2h,  16384);
  cvt_f32_f16<<<128, 256, 0, stream>>>(W_ih, Wihh, 32768);
  cvt_f32_f16<<<256, 256, 0, stream>>>(W_hh, Whhh, 65536);

  ode_lstm<<<B_TOT/BT, 512, 0, stream>>>(inputs, h0, c0, ts, b_ih, b_hh, b1, b2,
                                         W1h, W2h, Wihh, Whhh, out);
}

// Round 4
// 632.363 us; speedup vs baseline: 1.0438x; 1.0120x over previous
//
#include <hip/hip_runtime.h>

#define B_TOT 16384
#define HD 256
#define ID 128
#define BT 64            // two 32-row sub-tiles per block, pipelined in-wave
#define NSTEP 8
#define YP 264           // y/u LDS pitch (f16)
#define XP 136
#define HP 260           // master-h LDS pitch (f32): 260%32=4 -> max 4-way conflict

typedef float    f32x4  __attribute__((ext_vector_type(4)));
typedef float    f32x16 __attribute__((ext_vector_type(16)));
typedef _Float16 f16x8  __attribute__((ext_vector_type(8)));
typedef _Float16 f16x4  __attribute__((ext_vector_type(4)));
typedef _Float16 f16x2  __attribute__((ext_vector_type(2)));

__device__ __forceinline__ float fast_rcp(float x){ return __builtin_amdgcn_rcpf(x); }
__device__ __forceinline__ float fast_exp2(float x){ return __builtin_amdgcn_exp2f(x); }
__device__ __forceinline__ float fast_tanh(float x){
  return 1.0f - 2.0f*fast_rcp(1.0f + fast_exp2(x*2.8853900817779268f));
}
__device__ __forceinline__ float fast_sigmoid(float x){
  return fast_rcp(1.0f + fast_exp2(x*-1.4426950408889634f));
}

__global__ void cvt_f32_f16(const float* __restrict__ src, _Float16* __restrict__ dst, int n4){
  int i = blockIdx.x*256 + threadIdx.x;
  if (i < n4){
    float4 v = ((const float4*)src)[i];
    f16x4 t = {(_Float16)v.x, (_Float16)v.y, (_Float16)v.z, (_Float16)v.w};
    *(f16x4*)(dst + (size_t)i*4) = t;
  }
}

// acc element r: feat = 32*wv + 8*(r>>2) + 4*hh + (r&3), batch = l31
// Compaction: after each gemm chain the f32x16 acc collapses to f16x2[8]:
//   phase1 -> c1 = f16(tanh(acc))     (u, ready for LDS)
//   phase2 -> c2 = f16(dtv*acc)       (kd, dt-scaled slope)
// k-history rank compression (3 slots instead of 4):
//   slots: [0]=k1 [1]=k2 [2]=k3 until stage 3; at stage 3 (kd=k4) the only
//   future consumers of k1..k4 are the y6-row and b-row -> store
//   P1 = a6.k (slot0), P2 = b.k partial (slot1); slot2 dies.
__device__ __forceinline__ void cvt_tanh(const f32x16& a, f16x2 (&c)[8]){
  #pragma unroll
  for (int i = 0; i < 8; ++i){
    c[i][0] = (_Float16)fast_tanh(a[2*i]);
    c[i][1] = (_Float16)fast_tanh(a[2*i+1]);
  }
}
__device__ __forceinline__ void cvt_kd(const f32x16& a, float dtv, f16x2 (&c)[8]){
  #pragma unroll
  for (int i = 0; i < 8; ++i){
    c[i][0] = (_Float16)(dtv*a[2*i]);
    c[i][1] = (_Float16)(dtv*a[2*i+1]);
  }
}

// k-epilogue from compact kd (CK). Writes stage arg (f16) to YB; SIDX==5 also
// updates master h (f32 LDS). Per-lane h elements are lane-private.
#define EPI2C(CK, YB, HS, K, SIDX)                                         \
  { _Pragma("unroll")                                                      \
    for (int g2 = 0; g2 < 4; ++g2){                                        \
      f32x4 hv = *(const f32x4*)(HS + hoff + 8*g2);                        \
      f16x4 yv; f32x4 hnv;                                                 \
      _Pragma("unroll")                                                    \
      for (int r3 = 0; r3 < 4; ++r3){                                      \
        const int r = g2*4 + r3; const int pk = r>>1; const int hw = r&1;  \
        float kd = (float)CK[pk][hw];                                      \
        float yn;                                                          \
        if ((SIDX) == 0){                                                  \
          yn = hv[r3] + 0.2f*kd;                                           \
          K[0][pk][hw] = (_Float16)kd;                                     \
        } else if ((SIDX) == 1){                                           \
          float k0 = (float)K[0][pk][hw];                                  \
          yn = hv[r3] + 0.075f*k0 + 0.225f*kd;                             \
          K[1][pk][hw] = (_Float16)kd;                                     \
        } else if ((SIDX) == 2){                                           \
          float k0 = (float)K[0][pk][hw];                                  \
          float k1 = (float)K[1][pk][hw];                                  \
          yn = hv[r3] + (44.0f/45.0f)*k0 + (-56.0f/15.0f)*k1               \
             + (32.0f/9.0f)*kd;                                            \
          K[2][pk][hw] = (_Float16)kd;                                     \
        } else if ((SIDX) == 3){                                           \
          float k0 = (float)K[0][pk][hw];                                  \
          float k1 = (float)K[1][pk][hw];                                  \
          float k2 = (float)K[2][pk][hw];                                  \
          yn = hv[r3] + (19372.0f/6561.0f)*k0 + (-25360.0f/2187.0f)*k1     \
             + (64448.0f/6561.0f)*k2 + (-212.0f/729.0f)*kd;                \
          float P1 = (9017.0f/3168.0f)*k0 + (-355.0f/33.0f)*k1             \
                   + (46732.0f/5247.0f)*k2 + (49.0f/176.0f)*kd;            \
          float P2 = (35.0f/384.0f)*k0 + (500.0f/1113.0f)*k2               \
                   + (125.0f/192.0f)*kd;                                   \
          K[0][pk][hw] = (_Float16)P1;                                     \
          K[1][pk][hw] = (_Float16)P2;                                     \
        } else if ((SIDX) == 4){                                           \
          float p1 = (float)K[0][pk][hw];                                  \
          float p2 = (float)K[1][pk][hw];                                  \
          yn = hv[r3] + p1 + (-5103.0f/18656.0f)*kd;                       \
          K[1][pk][hw] = (_Float16)(p2 + (-2187.0f/6784.0f)*kd);           \
        } else {                                                           \
          float p2 = (float)K[1][pk][hw];                                  \
          yn = hv[r3] + p2 + (11.0f/84.0f)*kd;                             \
        }                                                                  \
        hnv[r3] = yn;                                                      \
        yv[r3] = (_Float16)yn;                                             \
      }                                                                    \
      if ((SIDX) == 5) *(f32x4*)(HS + hoff + 8*g2) = hnv;                  \
      *(f16x4*)(YB + yoff + 8*g2) = yv;                                    \
    }                                                                      \
  }

// u-epilogue: compact u (already tanh'd, f16) -> LDS write only
#define EPI1C(CU, YB)                                                      \
  { _Pragma("unroll")                                                      \
    for (int g2 = 0; g2 < 4; ++g2){                                        \
      f16x4 uv;                                                            \
      uv[0] = CU[g2*2][0];   uv[1] = CU[g2*2][1];                          \
      uv[2] = CU[g2*2+1][0]; uv[3] = CU[g2*2+1][1];                        \
      *(f16x4*)(YB + yoff + 8*g2) = uv;                                    \
    }                                                                      \
  }

// segments B,C,D of stage S (seg A is stage-specific: carries prev EPI2 of B)
#define SEGBCD(S)                                                          \
  { f32x16 a = gemm16(W1f, ybB, b1l); EPI1C(c1A, ybA); cvt_tanh(a, c1B); } \
  __syncthreads();                                                         \
  { f32x16 a = gemm16(W2f, ybA, b2l); EPI1C(c1B, ybB); cvt_kd(a, dtvA, c2A); } \
  __syncthreads();                                                         \
  { f32x16 a = gemm16(W2f, ybB, b2l); EPI2C(c2A, ybA, hslA, kpkA, S); cvt_kd(a, dtvB, c2B); } \
  __syncthreads();

#define STAGE4(S, SP)                                                      \
  { f32x16 a = gemm16(W1f, ybA, b1l); EPI2C(c2B, ybB, hslB, kpkB, SP); cvt_tanh(a, c1A); } \
  __syncthreads();                                                         \
  SEGBCD(S)

__global__ __launch_bounds__(512, 2)
void ode_lstm(const float* __restrict__ inputs, const float* __restrict__ h0,
              const float* __restrict__ c0,     const float* __restrict__ ts,
              const float* __restrict__ b_ih,   const float* __restrict__ b_hh,
              const float* __restrict__ b1,     const float* __restrict__ b2,
              const _Float16* __restrict__ W1h, const _Float16* __restrict__ W2h,
              const _Float16* __restrict__ Wihh,const _Float16* __restrict__ Whhh,
              float* __restrict__ out)
{
  __shared__ __align__(16) _Float16 ybA[32*YP], ybB[32*YP];  // y/u role-alternating
  __shared__ __align__(16) float    hslA[32*HP], hslB[32*HP];// master h (f32)
  __shared__ __align__(16) float    b1l[HD], b2l[HD], bsl[4*HD];
  __shared__ float dtl[BT];

  const int tid  = threadIdx.x;
  const int wv   = tid >> 6;
  const int lane = tid & 63;
  const int l31  = lane & 31;
  const int hh   = lane >> 5;
  const int row0 = blockIdx.x * BT;
  const int cb   = wv*32 + hh*4;
  const int yoff = l31*YP + cb;     // f16-elem offset (y/u buffers)
  const int hoff = l31*HP + cb;     // f32-elem offset (h buffers)

  if (tid < HD){ b1l[tid] = b1[tid]; b2l[tid] = b2[tid]; }
  bsl[tid]       = b_ih[tid]       + b_hh[tid];
  bsl[tid + 512] = b_ih[tid + 512] + b_hh[tid + 512];
  if (tid < BT) dtl[tid] = ts[row0 + tid] * (1.0f/NSTEP);

  // W1, W2 strips in VGPRs/AGPRs for the whole RK45 loop (128 regs; hard floor)
  f16x8 W1f[16], W2f[16];
  {
    const _Float16* w1p = W1h + (size_t)(wv*32 + l31)*HD + hh*8;
    const _Float16* w2p = W2h + (size_t)(wv*32 + l31)*HD + hh*8;
    #pragma unroll
    for (int kt = 0; kt < 16; ++kt){
      W1f[kt] = *(const f16x8*)(w1p + kt*16);
      W2f[kt] = *(const f16x8*)(w2p + kt*16);
    }
  }

  // h0 -> h LDS (f32) + y buffers (f16) for both sub-tiles
  #pragma unroll
  for (int g2 = 0; g2 < 4; ++g2){
    f32x4 ha = *(const f32x4*)(h0 + (size_t)(row0 + l31)*HD + cb + 8*g2);
    f32x4 hb = *(const f32x4*)(h0 + (size_t)(row0 + 32 + l31)*HD + cb + 8*g2);
    *(f32x4*)(hslA + hoff + 8*g2) = ha;
    *(f32x4*)(hslB + hoff + 8*g2) = hb;
    f16x4 ta = {(_Float16)ha[0],(_Float16)ha[1],(_Float16)ha[2],(_Float16)ha[3]};
    f16x4 tb = {(_Float16)hb[0],(_Float16)hb[1],(_Float16)hb[2],(_Float16)hb[3]};
    *(f16x4*)(ybA + yoff + 8*g2) = ta;
    *(f16x4*)(ybB + yoff + 8*g2) = tb;
  }
  __syncthreads();
  const float dtvA = dtl[l31], dtvB = dtl[32 + l31];

  // GEMM with bias-init C
  auto gemm16 = [&](const f16x8 (&Wf)[16], const _Float16* __restrict__ act,
                    const float* __restrict__ bL)->f32x16{
    f32x16 a;
    #pragma unroll
    for (int g2 = 0; g2 < 4; ++g2){
      f32x4 bv = *(const f32x4*)(bL + cb + 8*g2);
      a[g2*4+0] = bv[0]; a[g2*4+1] = bv[1]; a[g2*4+2] = bv[2]; a[g2*4+3] = bv[3];
    }
    const _Float16* bp = act + l31*YP + hh*8;
    #pragma unroll
    for (int kt = 0; kt < 16; ++kt){
      f16x8 Bf = *(const f16x8*)(bp + kt*16);
      a = __builtin_amdgcn_mfma_f32_32x32x16_f16(Wf[kt], Bf, a, 0, 0, 0);
    }
    return a;
  };

  // ================= RK45, two sub-tiles software-pipelined =================
  f16x2 c1A[8], c1B[8], c2A[8], c2B[8];     // compacts (8 regs each, ~2 live)
  f16x2 kpkA[3][8], kpkB[3][8];             // 24 regs each (rank-compressed)

  #pragma unroll 1
  for (int step = 0; step < NSTEP; ++step){
    { f32x16 a = gemm16(W1f, ybA, b1l);
      if (step > 0) { EPI2C(c2B, ybB, hslB, kpkB, 5); }
      cvt_tanh(a, c1A); }
    __syncthreads();
    SEGBCD(0)
    STAGE4(1, 0)
    STAGE4(2, 1)
    STAGE4(3, 2)
    STAGE4(4, 3)
    STAGE4(5, 4)
  }
  // flush: B's final stage-5 epilogue (h update + y = h)
  { EPI2C(c2B, ybB, hslB, kpkB, 5); }
  __syncthreads();

  // ================= two weight-shared LSTM cells, per sub-tile =============
  // h LDS region is dead now (final h lives as f16 in ybA/ybB) -> reuse for x and h1.
  _Float16* xA  = (_Float16*)hslA;
  _Float16* xB  = (_Float16*)hslB;
  _Float16* h1A = ((_Float16*)hslA) + 32*XP;
  _Float16* h1B = ((_Float16*)hslB) + 32*XP;

  #pragma unroll
  for (int it = 0; it < 4; ++it){
    int idx = tid + it*512;                 // 64 rows * 32 float4
    int r = idx >> 5, c4 = idx & 31;
    float4 v = ((const float4*)inputs)[(size_t)(row0 + r)*(ID/4) + c4];
    f16x4 t = {(_Float16)v.x, (_Float16)v.y, (_Float16)v.z, (_Float16)v.w};
    _Float16* xd = (r < 32) ? xA : xB;
    *(f16x4*)(xd + (r & 31)*XP + c4*4) = t;
  }
  __syncthreads();

  #pragma unroll 1
  for (int sb = 0; sb < 2; ++sb){
    const _Float16* xs  = sb ? xB  : xA;
    const _Float16* hod = sb ? ybB : ybA;
    _Float16*       h1  = sb ? h1B : h1A;
    const int rbase = row0 + sb*32;

    // x-part of gates (shared by both cells), bias-init with b_ih+b_hh
    f32x16 agx[4];
    #pragma unroll
    for (int g = 0; g < 4; ++g){
      #pragma unroll
      for (int g2 = 0; g2 < 4; ++g2){
        f32x4 bv = *(const f32x4*)(bsl + g*HD + cb + 8*g2);
        agx[g][g2*4+0] = bv[0]; agx[g][g2*4+1] = bv[1];
        agx[g][g2*4+2] = bv[2]; agx[g][g2*4+3] = bv[3];
      }
    }
    {
      const _Float16* bp = xs + l31*XP + hh*8;
      #pragma unroll 2
      for (int kt = 0; kt < 8; ++kt){
        f16x8 Bf = *(const f16x8*)(bp + kt*16);
        #pragma unroll
        for (int g = 0; g < 4; ++g){
          f16x8 Af = *(const f16x8*)(Wihh + (size_t)(g*HD + wv*32 + l31)*ID + kt*16 + hh*8);
          agx[g] = __builtin_amdgcn_mfma_f32_32x32x16_f16(Af, Bf, agx[g], 0, 0, 0);
        }
      }
    }
    f32x4 c4v[4];
    #pragma unroll
    for (int g2 = 0; g2 < 4; ++g2)
      c4v[g2] = *(const f32x4*)(c0 + (size_t)(rbase + l31)*HD + cb + 8*g2);

    #pragma unroll 1
    for (int cell = 0; cell < 2; ++cell){
      f32x16 ag[4];
      #pragma unroll
      for (int g = 0; g < 4; ++g) ag[g] = agx[g];
      const _Float16* hb = (cell == 0) ? hod : h1;
      const _Float16* bp = hb + l31*YP + hh*8;
      #pragma unroll 2
      for (int kt = 0; kt < 16; ++kt){
        f16x8 Bf = *(const f16x8*)(bp + kt*16);
        #pragma unroll
        for (int g = 0; g < 4; ++g){
          f16x8 Af = *(const f16x8*)(Whhh + (size_t)(g*HD + wv*32 + l31)*HD + kt*16 + hh*8);
          ag[g] = __builtin_amdgcn_mfma_f32_32x32x16_f16(Af, Bf, ag[g], 0, 0, 0);
        }
      }
      #pragma unroll
      for (int g2 = 0; g2 < 4; ++g2){
        f16x4 hv16; f32x4 ho, co;
        #pragma unroll
        for (int r3 = 0; r3 < 4; ++r3){
          const int r = g2*4 + r3;
          float iv = fast_sigmoid(ag[0][r]);
          float fv = fast_sigmoid(ag[1][r]);
          float gv = fast_tanh   (ag[2][r]);
          float ov = fast_sigmoid(ag[3][r]);
          float cn = fv*c4v[g2][r3] + iv*gv;
          c4v[g2][r3] = cn;
          float hn = ov*fast_tanh(cn);
          hv16[r3] = (_Float16)hn; ho[r3] = hn; co[r3] = cn;
        }
        if (cell == 0){
          *(f16x4*)(h1 + yoff + 8*g2) = hv16;        // h1 -> cell2 input
        } else {
          size_t o = (size_t)(rbase + l31)*HD + cb + 8*g2;
          *(f32x4*)(out + o) = ho;                   // h2
          *(f32x4*)(out + (size_t)B_TOT*HD + o) = co;// c2
        }
      }
      if (cell == 0) __syncthreads();
    }
  }
}

extern "C" void kernel_launch(void* const* d_in, const int* in_sizes, int n_in,
                              void* d_out, int out_size, void* d_ws, size_t ws_size,
                              hipStream_t stream) {
  (void)in_sizes; (void)n_in; (void)out_size; (void)ws_size;
  const float* inputs = (const float*)d_in[0];
  const float* h0     = (const float*)d_in[1];
  const float* c0     = (const float*)d_in[2];
  const float* ts     = (const float*)d_in[3];
  const float* W_ih   = (const float*)d_in[4];
  const float* W_hh   = (const float*)d_in[5];
  const float* b_ih   = (const float*)d_in[6];
  const float* b_hh   = (const float*)d_in[7];
  const float* W1     = (const float*)d_in[8];
  const float* b1     = (const float*)d_in[9];
  const float* W2     = (const float*)d_in[10];
  const float* b2     = (const float*)d_in[11];
  float* out = (float*)d_out;

  _Float16* wsh  = (_Float16*)d_ws;
  _Float16* W1h  = wsh;             // 65536
  _Float16* W2h  = wsh + 65536;     // 65536
  _Float16* Wihh = wsh + 131072;    // 131072
  _Float16* Whhh = wsh + 262144;    // 262144  (total 1 MB)

  cvt_f32_f16<<<64,  256, 0, stream>>>(W1,   W1h,  16384);
  cvt_f32_f16<<<64,  256, 0, stream>>>(W2,   W2h,  16384);
  cvt_f32_f16<<<128, 256, 0, stream>>>(W_ih, Wihh, 32768);
  cvt_f32_f16<<<256, 256, 0, stream>>>(W_hh, Whhh, 65536);

  ode_lstm<<<B_TOT/BT, 512, 0, stream>>>(inputs, h0, c0, ts, b_ih, b_hh, b1, b2,
                                         W1h, W2h, Wihh, Whhh, out);
}

// Round 5
// 457.530 us; speedup vs baseline: 1.4427x; 1.3821x over previous
//
#include <hip/hip_runtime.h>

#define B_TOT 16384
#define HD 256
#define ID 128
#define BT 32
#define NSTEP 8
#define YP 264   // y/u LDS pitch (f16): 132 dwords == 4 banks/row shift, balanced for b128/b64
#define XP 136

typedef float    f32x4  __attribute__((ext_vector_type(4)));
typedef float    f32x16 __attribute__((ext_vector_type(16)));
typedef _Float16 f16x8  __attribute__((ext_vector_type(8)));
typedef _Float16 f16x4  __attribute__((ext_vector_type(4)));
typedef _Float16 f16x2  __attribute__((ext_vector_type(2)));

__device__ __forceinline__ float fast_rcp(float x){ return __builtin_amdgcn_rcpf(x); }
__device__ __forceinline__ float fast_exp2(float x){ return __builtin_amdgcn_exp2f(x); }
__device__ __forceinline__ float fast_tanh(float x){
  return 1.0f - 2.0f*fast_rcp(1.0f + fast_exp2(x*2.8853900817779268f));
}
__device__ __forceinline__ float fast_sigmoid(float x){
  return fast_rcp(1.0f + fast_exp2(x*-1.4426950408889634f));
}

__global__ void cvt_f32_f16(const float* __restrict__ src, _Float16* __restrict__ dst, int n4){
  int i = blockIdx.x*256 + threadIdx.x;
  if (i < n4){
    float4 v = ((const float4*)src)[i];
    f16x4 t = {(_Float16)v.x, (_Float16)v.y, (_Float16)v.z, (_Float16)v.w};
    *(f16x4*)(dst + (size_t)i*4) = t;
  }
}

// element r of f32x16 acc: feat = 32*wv + 8*(r>>2) + 4*hh + (r&3), batch = l31
#define KP(i) ((float)kpk[i][pk][hw])

__global__ __launch_bounds__(512, 2)
void ode_lstm(const float* __restrict__ inputs, const float* __restrict__ h0,
              const float* __restrict__ c0,     const float* __restrict__ ts,
              const float* __restrict__ b_ih,   const float* __restrict__ b_hh,
              const float* __restrict__ b1,     const float* __restrict__ b2,
              const _Float16* __restrict__ W1h, const _Float16* __restrict__ W2h,
              const _Float16* __restrict__ Wihh,const _Float16* __restrict__ Whhh,
              float* __restrict__ out)
{
  __shared__ __align__(16) _Float16 yl[BT*YP];
  __shared__ __align__(16) _Float16 ul[BT*YP];
  __shared__ __align__(16) _Float16 xl[BT*XP];
  __shared__ __align__(16) float b1l[HD], b2l[HD], bsl[4*HD];
  __shared__ float dtl[BT];

  const int tid  = threadIdx.x;
  const int wv   = tid >> 6;        // 8 waves: feature strip 32*wv
  const int lane = tid & 63;
  const int l31  = lane & 31;       // batch row owned by this lane (C-layout col)
  const int hh   = lane >> 5;       // k-half for A/B operands; +4 feat offset in C/D
  const int row0 = blockIdx.x * BT;
  const int cb   = wv*32 + hh*4;    // lane feature base; +8*g2 per acc group
  const int yrow = l31*YP + cb;     // LDS elem offset for this lane's stage writes

  // ---- prologue staging ----
  #pragma unroll
  for (int it = 0; it < 2; ++it){
    int idx = tid + it*512;                 // 32 rows * 32 float4
    int r = idx >> 5, c4 = idx & 31;
    float4 v = ((const float4*)inputs)[(size_t)(row0 + r)*(ID/4) + c4];
    f16x4 t = {(_Float16)v.x, (_Float16)v.y, (_Float16)v.z, (_Float16)v.w};
    *(f16x4*)(xl + r*XP + c4*4) = t;
  }
  if (tid < HD){ b1l[tid] = b1[tid]; b2l[tid] = b2[tid]; }
  bsl[tid]       = b_ih[tid]       + b_hh[tid];
  bsl[tid + 512] = b_ih[tid + 512] + b_hh[tid + 512];
  if (tid < BT) dtl[tid] = ts[row0 + tid] * (1.0f/NSTEP);

  // ---- W1, W2 strips held in VGPRs for the whole RK45 loop ----
  f16x8 W1f[16], W2f[16];
  {
    const _Float16* w1p = W1h + (size_t)(wv*32 + l31)*HD + hh*8;
    const _Float16* w2p = W2h + (size_t)(wv*32 + l31)*HD + hh*8;
    #pragma unroll
    for (int kt = 0; kt < 16; ++kt){
      W1f[kt] = *(const f16x8*)(w1p + kt*16);
      W2f[kt] = *(const f16x8*)(w2p + kt*16);
    }
  }

  // ---- master h (fp32 regs) + initial y = h0 ----
  f32x4 h4[4];
  #pragma unroll
  for (int g2 = 0; g2 < 4; ++g2){
    f32x4 hv = *(const f32x4*)(h0 + (size_t)(row0 + l31)*HD + cb + 8*g2);
    h4[g2] = hv;
    f16x4 t = {(_Float16)hv[0], (_Float16)hv[1], (_Float16)hv[2], (_Float16)hv[3]};
    *(f16x4*)(yl + yrow + 8*g2) = t;
  }
  __syncthreads();
  const float dtv = dtl[l31];

  // GEMM: TWO independent 8-deep accumulator chains (even/odd k-tiles) so the
  // MFMA pipe overlaps chain latency (the 16-deep dependent chain was the
  // dominant stall: ~38cy pipe occupancy per MFMA at 2 lockstep waves/SIMD).
  // Chain a is bias-initialized (C-in = bias), chain b starts at 0; a+b at end.
  auto gemm16 = [&](const f16x8 (&Wf)[16], const _Float16* __restrict__ act,
                    const float* __restrict__ bL)->f32x16{
    f32x16 a, b = {};
    #pragma unroll
    for (int g2 = 0; g2 < 4; ++g2){
      f32x4 bv = *(const f32x4*)(bL + cb + 8*g2);
      a[g2*4+0] = bv[0]; a[g2*4+1] = bv[1]; a[g2*4+2] = bv[2]; a[g2*4+3] = bv[3];
    }
    const _Float16* bp = act + l31*YP + hh*8;
    #pragma unroll
    for (int kt = 0; kt < 8; ++kt){
      f16x8 B0 = *(const f16x8*)(bp + (2*kt)*16);
      f16x8 B1 = *(const f16x8*)(bp + (2*kt+1)*16);
      a = __builtin_amdgcn_mfma_f32_32x32x16_f16(Wf[2*kt],   B0, a, 0, 0, 0);
      b = __builtin_amdgcn_mfma_f32_32x32x16_f16(Wf[2*kt+1], B1, b, 0, 0, 0);
    }
    return a + b;
  };

  // phase1: u = tanh(W1 y + b1) -> ul   (bias already in acc)
  auto phase1 = [&](){
    f32x16 a = gemm16(W1f, yl, b1l);
    #pragma unroll
    for (int g2 = 0; g2 < 4; ++g2){
      f16x4 uv;
      #pragma unroll
      for (int r3 = 0; r3 < 4; ++r3)
        uv[r3] = (_Float16)fast_tanh(a[g2*4 + r3]);
      *(f16x4*)(ul + yrow + 8*g2) = uv;
    }
    __syncthreads();
  };

  #define STAGE(SIDX, YEXPR)                                              \
    phase1();                                                             \
    { f32x16 a2 = gemm16(W2f, ul, b2l);                                   \
      _Pragma("unroll")                                                   \
      for (int g2 = 0; g2 < 4; ++g2){                                     \
        f16x4 yv;                                                         \
        _Pragma("unroll")                                                 \
        for (int r3 = 0; r3 < 4; ++r3){                                   \
          const int r = g2*4 + r3; const int pk = r>>1; const int hw = r&1;\
          float kd = dtv*a2[r];                                           \
          if (SIDX < 5) kpk[SIDX][pk][hw] = (_Float16)kd;                 \
          yv[r3] = (_Float16)(YEXPR);                                     \
        }                                                                 \
        *(f16x4*)(yl + yrow + 8*g2) = yv;                                 \
      }                                                                   \
    }                                                                     \
    __syncthreads();

  // ================= RK45 (Dormand-Prince) =================
  #pragma unroll 1
  for (int step = 0; step < NSTEP; ++step){
    f16x2 kpk[5][8];   // dt-scaled slopes k1..k5, f16-packed, 40 VGPR

    STAGE(0, h4[g2][r3] + 0.2f*kd)
    STAGE(1, h4[g2][r3] + 0.075f*KP(0) + 0.225f*kd)
    STAGE(2, h4[g2][r3] + (44.0f/45.0f)*KP(0) + (-56.0f/15.0f)*KP(1)
                        + (32.0f/9.0f)*kd)
    STAGE(3, h4[g2][r3] + (19372.0f/6561.0f)*KP(0) + (-25360.0f/2187.0f)*KP(1)
                        + (64448.0f/6561.0f)*KP(2) + (-212.0f/729.0f)*kd)
    STAGE(4, h4[g2][r3] + (9017.0f/3168.0f)*KP(0) + (-355.0f/33.0f)*KP(1)
                        + (46732.0f/5247.0f)*KP(2) + (49.0f/176.0f)*KP(3)
                        + (-5103.0f/18656.0f)*kd)
    // final stage: update master h, write y = h (next step / LSTM h-in)
    phase1();
    { f32x16 a2 = gemm16(W2f, ul, b2l);
      #pragma unroll
      for (int g2 = 0; g2 < 4; ++g2){
        f16x4 yv;
        #pragma unroll
        for (int r3 = 0; r3 < 4; ++r3){
          const int r = g2*4 + r3; const int pk = r>>1; const int hw = r&1;
          float kd = dtv*a2[r];
          float hn = h4[g2][r3] + (35.0f/384.0f)*KP(0) + (500.0f/1113.0f)*KP(2)
                   + (125.0f/192.0f)*KP(3) + (-2187.0f/6784.0f)*KP(4)
                   + (11.0f/84.0f)*kd;
          h4[g2][r3] = hn;
          yv[r3] = (_Float16)hn;
        }
        *(f16x4*)(yl + yrow + 8*g2) = yv;
      }
    }
    __syncthreads();
  }

  // ================= two weight-shared LSTM cells =================
  // x-part of the gates is identical for both cells: compute once.
  // Bias-init (b_ih+b_hh) in the acc; 4 independent chains (g) already
  // give the MFMA pipe enough ILP here.
  f32x16 agx[4];
  #pragma unroll
  for (int g = 0; g < 4; ++g){
    #pragma unroll
    for (int g2 = 0; g2 < 4; ++g2){
      f32x4 bv = *(const f32x4*)(bsl + g*HD + cb + 8*g2);
      agx[g][g2*4+0] = bv[0]; agx[g][g2*4+1] = bv[1];
      agx[g][g2*4+2] = bv[2]; agx[g][g2*4+3] = bv[3];
    }
  }
  {
    const _Float16* bp = xl + l31*XP + hh*8;
    #pragma unroll 2
    for (int kt = 0; kt < 8; ++kt){
      f16x8 Bf = *(const f16x8*)(bp + kt*16);
      #pragma unroll
      for (int g = 0; g < 4; ++g){
        f16x8 Af = *(const f16x8*)(Wihh + (size_t)(g*HD + wv*32 + l31)*ID + kt*16 + hh*8);
        agx[g] = __builtin_amdgcn_mfma_f32_32x32x16_f16(Af, Bf, agx[g], 0, 0, 0);
      }
    }
  }
  f32x4 c4[4];
  #pragma unroll
  for (int g2 = 0; g2 < 4; ++g2)
    c4[g2] = *(const f32x4*)(c0 + (size_t)(row0 + l31)*HD + cb + 8*g2);

  #pragma unroll 1
  for (int cell = 0; cell < 2; ++cell){
    f32x16 ag[4];
    #pragma unroll
    for (int g = 0; g < 4; ++g) ag[g] = agx[g];
    const _Float16* hsrc = (cell == 0) ? yl : ul;
    const _Float16* bp = hsrc + l31*YP + hh*8;
    #pragma unroll 2
    for (int kt = 0; kt < 16; ++kt){
      f16x8 Bf = *(const f16x8*)(bp + kt*16);
      #pragma unroll
      for (int g = 0; g < 4; ++g){
        f16x8 Af = *(const f16x8*)(Whhh + (size_t)(g*HD + wv*32 + l31)*HD + kt*16 + hh*8);
        ag[g] = __builtin_amdgcn_mfma_f32_32x32x16_f16(Af, Bf, ag[g], 0, 0, 0);
      }
    }
    #pragma unroll
    for (int g2 = 0; g2 < 4; ++g2){
      f16x4 hv; f32x4 ho, co;
      #pragma unroll
      for (int r3 = 0; r3 < 4; ++r3){
        const int r = g2*4 + r3;
        float iv = fast_sigmoid(ag[0][r]);
        float fv = fast_sigmoid(ag[1][r]);
        float gv = fast_tanh   (ag[2][r]);
        float ov = fast_sigmoid(ag[3][r]);
        float cn = fv*c4[g2][r3] + iv*gv;
        c4[g2][r3] = cn;
        float hn = ov*fast_tanh(cn);
        hv[r3] = (_Float16)hn; ho[r3] = hn; co[r3] = cn;
      }
      if (cell == 0){
        *(f16x4*)(ul + yrow + 8*g2) = hv;          // h1 -> cell2 input
      } else {
        size_t o = (size_t)(row0 + l31)*HD + cb + 8*g2;
        *(f32x4*)(out + o) = ho;                   // h2
        *(f32x4*)(out + (size_t)B_TOT*HD + o) = co;// c2
      }
    }
    if (cell == 0) __syncthreads();
  }
}

extern "C" void kernel_launch(void* const* d_in, const int* in_sizes, int n_in,
                              void* d_out, int out_size, void* d_ws, size_t ws_size,
                              hipStream_t stream) {
  (void)in_sizes; (void)n_in; (void)out_size; (void)ws_size;
  const float* inputs = (const float*)d_in[0];
  const float* h0     = (const float*)d_in[1];
  const float* c0     = (const float*)d_in[2];
  const float* ts     = (const float*)d_in[3];
  const float* W_ih   = (const float*)d_in[4];
  const float* W_hh   = (const float*)d_in[5];
  const float* b_ih   = (const float*)d_in[6];
  const float* b_hh   = (const float*)d_in[7];
  const float* W1     = (const float*)d_in[8];
  const float* b1     = (const float*)d_in[9];
  const float* W2     = (const float*)d_in[10];
  const float* b2     = (const float*)d_in[11];
  float* out = (float*)d_out;

  _Float16* wsh  = (_Float16*)d_ws;
  _Float16* W1h  = wsh;             // 65536
  _Float16* W2h  = wsh + 65536;     // 65536
  _Float16* Wihh = wsh + 131072;    // 131072
  _Float16* Whhh = wsh + 262144;    // 262144  (total 1 MB)

  cvt_f32_f16<<<64,  256, 0, stream>>>(W1,   W1h,  16384);
  cvt_f32_f16<<<64,  256, 0, stream>>>(W2,   W2h,  16384);
  cvt_f32_f16<<<128, 256, 0, stream>>>(W_ih, Wihh, 32768);
  cvt_f32_f16<<<256, 256, 0, stream>>>(W_hh, Whhh, 65536);

  ode_lstm<<<B_TOT/BT, 512, 0, stream>>>(inputs, h0, c0, ts, b_ih, b_hh, b1, b2,
                                         W1h, W2h, Wihh, Whhh, out);
}

// Round 6
// 417.754 us; speedup vs baseline: 1.5801x; 1.0952x over previous
//
#include <hip/hip_runtime.h>

#define B_TOT 16384
#define HD 256
#define ID 128
#define BT 32
#define NSTEP 8
#define YP 264   // y/u LDS pitch (f16)
#define XP 136
#define HP 260   // master-h LDS pitch (f32): 16B-aligned rows, worst 4-way conflict

typedef float    f32x4  __attribute__((ext_vector_type(4)));
typedef float    f32x16 __attribute__((ext_vector_type(16)));
typedef _Float16 f16x8  __attribute__((ext_vector_type(8)));
typedef _Float16 f16x4  __attribute__((ext_vector_type(4)));
typedef _Float16 f16x2  __attribute__((ext_vector_type(2)));

__device__ __forceinline__ float fast_rcp(float x){ return __builtin_amdgcn_rcpf(x); }
__device__ __forceinline__ float fast_exp2(float x){ return __builtin_amdgcn_exp2f(x); }
__device__ __forceinline__ float fast_tanh(float x){
  return 1.0f - 2.0f*fast_rcp(1.0f + fast_exp2(x*2.8853900817779268f));
}
__device__ __forceinline__ float fast_sigmoid(float x){
  return fast_rcp(1.0f + fast_exp2(x*-1.4426950408889634f));
}

__global__ void cvt_f32_f16(const float* __restrict__ src, _Float16* __restrict__ dst, int n4){
  int i = blockIdx.x*256 + threadIdx.x;
  if (i < n4){
    float4 v = ((const float4*)src)[i];
    f16x4 t = {(_Float16)v.x, (_Float16)v.y, (_Float16)v.z, (_Float16)v.w};
    *(f16x4*)(dst + (size_t)i*4) = t;
  }
}

// element r of f32x16 acc: feat = 32*wv + 8*(r>>2) + 4*hh + (r&3), batch = l31
#define KP(i) ((float)kpk[i][pk][hw])

__global__ __launch_bounds__(512, 2)
void ode_lstm(const float* __restrict__ inputs, const float* __restrict__ h0,
              const float* __restrict__ c0,     const float* __restrict__ ts,
              const float* __restrict__ b_ih,   const float* __restrict__ b_hh,
              const float* __restrict__ b1,     const float* __restrict__ b2,
              const _Float16* __restrict__ W1h, const _Float16* __restrict__ W2h,
              const _Float16* __restrict__ Wihh,const _Float16* __restrict__ Whhh,
              float* __restrict__ out)
{
  __shared__ __align__(16) _Float16 yl[BT*YP];
  __shared__ __align__(16) _Float16 ul[BT*YP];
  __shared__ __align__(16) _Float16 xl[BT*XP];
  __shared__ __align__(16) float    hsl[BT*HP];   // master h (f32, lane-private elems)
  __shared__ __align__(16) float b1l[HD], b2l[HD], bsl[4*HD];
  __shared__ float dtl[BT];

  const int tid  = threadIdx.x;
  const int wv   = tid >> 6;        // 8 waves: feature strip 32*wv
  const int lane = tid & 63;
  const int l31  = lane & 31;       // batch row owned by this lane (C-layout col)
  const int hh   = lane >> 5;       // k-half for A/B operands; +4 feat offset in C/D
  const int row0 = blockIdx.x * BT;
  const int cb   = wv*32 + hh*4;    // lane feature base; +8*g2 per acc group
  const int yrow = l31*YP + cb;     // LDS elem offset (f16) for stage writes
  const int hoff = l31*HP + cb;     // LDS elem offset (f32) for master h

  // ---- prologue staging ----
  #pragma unroll
  for (int it = 0; it < 2; ++it){
    int idx = tid + it*512;                 // 32 rows * 32 float4
    int r = idx >> 5, c4 = idx & 31;
    float4 v = ((const float4*)inputs)[(size_t)(row0 + r)*(ID/4) + c4];
    f16x4 t = {(_Float16)v.x, (_Float16)v.y, (_Float16)v.z, (_Float16)v.w};
    *(f16x4*)(xl + r*XP + c4*4) = t;
  }
  if (tid < HD){ b1l[tid] = b1[tid]; b2l[tid] = b2[tid]; }
  bsl[tid]       = b_ih[tid]       + b_hh[tid];
  bsl[tid + 512] = b_ih[tid + 512] + b_hh[tid + 512];
  if (tid < BT) dtl[tid] = ts[row0 + tid] * (1.0f/NSTEP);

  // ---- W1, W2 strips held in VGPRs for the whole RK45 loop ----
  f16x8 W1f[16], W2f[16];
  {
    const _Float16* w1p = W1h + (size_t)(wv*32 + l31)*HD + hh*8;
    const _Float16* w2p = W2h + (size_t)(wv*32 + l31)*HD + hh*8;
    #pragma unroll
    for (int kt = 0; kt < 16; ++kt){
      W1f[kt] = *(const f16x8*)(w1p + kt*16);
      W2f[kt] = *(const f16x8*)(w2p + kt*16);
    }
  }

  // ---- master h -> LDS (f32), initial y = h0 (f16) ----
  #pragma unroll
  for (int g2 = 0; g2 < 4; ++g2){
    f32x4 hv = *(const f32x4*)(h0 + (size_t)(row0 + l31)*HD + cb + 8*g2);
    *(f32x4*)(hsl + hoff + 8*g2) = hv;
    f16x4 t = {(_Float16)hv[0], (_Float16)hv[1], (_Float16)hv[2], (_Float16)hv[3]};
    *(f16x4*)(yl + yrow + 8*g2) = t;
  }
  __syncthreads();
  const float dtv = dtl[l31];

  // GEMM: TWO independent 8-deep accumulator chains (even/odd k-tiles) to halve
  // exposed MFMA chain latency. Chain a bias-initialized; a+b at end.
  auto gemm16 = [&](const f16x8 (&Wf)[16], const _Float16* __restrict__ act,
                    const float* __restrict__ bL)->f32x16{
    f32x16 a, b = {};
    #pragma unroll
    for (int g2 = 0; g2 < 4; ++g2){
      f32x4 bv = *(const f32x4*)(bL + cb + 8*g2);
      a[g2*4+0] = bv[0]; a[g2*4+1] = bv[1]; a[g2*4+2] = bv[2]; a[g2*4+3] = bv[3];
    }
    const _Float16* bp = act + l31*YP + hh*8;
    #pragma unroll
    for (int kt = 0; kt < 8; ++kt){
      f16x8 B0 = *(const f16x8*)(bp + (2*kt)*16);
      f16x8 B1 = *(const f16x8*)(bp + (2*kt+1)*16);
      a = __builtin_amdgcn_mfma_f32_32x32x16_f16(Wf[2*kt],   B0, a, 0, 0, 0);
      b = __builtin_amdgcn_mfma_f32_32x32x16_f16(Wf[2*kt+1], B1, b, 0, 0, 0);
    }
    return a + b;
  };

  // phase1: u = tanh(W1 y + b1) -> ul   (bias already in acc)
  auto phase1 = [&](){
    f32x16 a = gemm16(W1f, yl, b1l);
    #pragma unroll
    for (int g2 = 0; g2 < 4; ++g2){
      f16x4 uv;
      #pragma unroll
      for (int r3 = 0; r3 < 4; ++r3)
        uv[r3] = (_Float16)fast_tanh(a[g2*4 + r3]);
      *(f16x4*)(ul + yrow + 8*g2) = uv;
    }
    __syncthreads();
  };

  #define STAGE(SIDX, YEXPR)                                              \
    phase1();                                                             \
    { f32x16 a2 = gemm16(W2f, ul, b2l);                                   \
      _Pragma("unroll")                                                   \
      for (int g2 = 0; g2 < 4; ++g2){                                     \
        f32x4 hv = *(const f32x4*)(hsl + hoff + 8*g2);                    \
        f16x4 yv;                                                         \
        _Pragma("unroll")                                                 \
        for (int r3 = 0; r3 < 4; ++r3){                                   \
          const int r = g2*4 + r3; const int pk = r>>1; const int hw = r&1;\
          float kd = dtv*a2[r];                                           \
          if (SIDX < 5) kpk[SIDX][pk][hw] = (_Float16)kd;                 \
          yv[r3] = (_Float16)(YEXPR);                                     \
        }                                                                 \
        *(f16x4*)(yl + yrow + 8*g2) = yv;                                 \
      }                                                                   \
    }                                                                     \
    __syncthreads();

  // ================= RK45 (Dormand-Prince) =================
  #pragma unroll 1
  for (int step = 0; step < NSTEP; ++step){
    f16x2 kpk[5][8];   // dt-scaled slopes k1..k5, f16-packed, 40 VGPR

    STAGE(0, hv[r3] + 0.2f*kd)
    STAGE(1, hv[r3] + 0.075f*KP(0) + 0.225f*kd)
    STAGE(2, hv[r3] + (44.0f/45.0f)*KP(0) + (-56.0f/15.0f)*KP(1)
                    + (32.0f/9.0f)*kd)
    STAGE(3, hv[r3] + (19372.0f/6561.0f)*KP(0) + (-25360.0f/2187.0f)*KP(1)
                    + (64448.0f/6561.0f)*KP(2) + (-212.0f/729.0f)*kd)
    STAGE(4, hv[r3] + (9017.0f/3168.0f)*KP(0) + (-355.0f/33.0f)*KP(1)
                    + (46732.0f/5247.0f)*KP(2) + (49.0f/176.0f)*KP(3)
                    + (-5103.0f/18656.0f)*kd)
    // final stage: update master h (LDS), write y = h (next step / LSTM h-in)
    phase1();
    { f32x16 a2 = gemm16(W2f, ul, b2l);
      #pragma unroll
      for (int g2 = 0; g2 < 4; ++g2){
        f32x4 hv = *(const f32x4*)(hsl + hoff + 8*g2);
        f16x4 yv; f32x4 hnv;
        #pragma unroll
        for (int r3 = 0; r3 < 4; ++r3){
          const int r = g2*4 + r3; const int pk = r>>1; const int hw = r&1;
          float kd = dtv*a2[r];
          float hn = hv[r3] + (35.0f/384.0f)*KP(0) + (500.0f/1113.0f)*KP(2)
                   + (125.0f/192.0f)*KP(3) + (-2187.0f/6784.0f)*KP(4)
                   + (11.0f/84.0f)*kd;
          hnv[r3] = hn;
          yv[r3] = (_Float16)hn;
        }
        *(f32x4*)(hsl + hoff + 8*g2) = hnv;
        *(f16x4*)(yl + yrow + 8*g2) = yv;
      }
    }
    __syncthreads();
  }

  // ================= two weight-shared LSTM cells =================
  // x-part of the gates is identical for both cells: compute once.
  f32x16 agx[4];
  #pragma unroll
  for (int g = 0; g < 4; ++g){
    #pragma unroll
    for (int g2 = 0; g2 < 4; ++g2){
      f32x4 bv = *(const f32x4*)(bsl + g*HD + cb + 8*g2);
      agx[g][g2*4+0] = bv[0]; agx[g][g2*4+1] = bv[1];
      agx[g][g2*4+2] = bv[2]; agx[g][g2*4+3] = bv[3];
    }
  }
  {
    const _Float16* bp = xl + l31*XP + hh*8;
    #pragma unroll 2
    for (int kt = 0; kt < 8; ++kt){
      f16x8 Bf = *(const f16x8*)(bp + kt*16);
      #pragma unroll
      for (int g = 0; g < 4; ++g){
        f16x8 Af = *(const f16x8*)(Wihh + (size_t)(g*HD + wv*32 + l31)*ID + kt*16 + hh*8);
        agx[g] = __builtin_amdgcn_mfma_f32_32x32x16_f16(Af, Bf, agx[g], 0, 0, 0);
      }
    }
  }
  f32x4 c4[4];
  #pragma unroll
  for (int g2 = 0; g2 < 4; ++g2)
    c4[g2] = *(const f32x4*)(c0 + (size_t)(row0 + l31)*HD + cb + 8*g2);

  #pragma unroll 1
  for (int cell = 0; cell < 2; ++cell){
    f32x16 ag[4];
    #pragma unroll
    for (int g = 0; g < 4; ++g) ag[g] = agx[g];
    const _Float16* hsrc = (cell == 0) ? yl : ul;
    const _Float16* bp = hsrc + l31*YP + hh*8;
    #pragma unroll 2
    for (int kt = 0; kt < 16; ++kt){
      f16x8 Bf = *(const f16x8*)(bp + kt*16);
      #pragma unroll
      for (int g = 0; g < 4; ++g){
        f16x8 Af = *(const f16x8*)(Whhh + (size_t)(g*HD + wv*32 + l31)*HD + kt*16 + hh*8);
        ag[g] = __builtin_amdgcn_mfma_f32_32x32x16_f16(Af, Bf, ag[g], 0, 0, 0);
      }
    }
    #pragma unroll
    for (int g2 = 0; g2 < 4; ++g2){
      f16x4 hv16; f32x4 ho, co;
      #pragma unroll
      for (int r3 = 0; r3 < 4; ++r3){
        const int r = g2*4 + r3;
        float iv = fast_sigmoid(ag[0][r]);
        float fv = fast_sigmoid(ag[1][r]);
        float gv = fast_tanh   (ag[2][r]);
        float ov = fast_sigmoid(ag[3][r]);
        float cn = fv*c4[g2][r3] + iv*gv;
        c4[g2][r3] = cn;
        float hn = ov*fast_tanh(cn);
        hv16[r3] = (_Float16)hn; ho[r3] = hn; co[r3] = cn;
      }
      if (cell == 0){
        *(f16x4*)(ul + yrow + 8*g2) = hv16;        // h1 -> cell2 input
      } else {
        size_t o = (size_t)(row0 + l31)*HD + cb + 8*g2;
        *(f32x4*)(out + o) = ho;                   // h2
        *(f32x4*)(out + (size_t)B_TOT*HD + o) = co;// c2
      }
    }
    if (cell == 0) __syncthreads();
  }
}

extern "C" void kernel_launch(void* const* d_in, const int* in_sizes, int n_in,
                              void* d_out, int out_size, void* d_ws, size_t ws_size,
                              hipStream_t stream) {
  (void)in_sizes; (void)n_in; (void)out_size; (void)ws_size;
  const float* inputs = (const float*)d_in[0];
  const float* h0     = (const float*)d_in[1];
  const float* c0     = (const float*)d_in[2];
  const float* ts     = (const float*)d_in[3];
  const float* W_ih   = (const float*)d_in[4];
  const float* W_hh   = (const float*)d_in[5];
  const float* b_ih   = (const float*)d_in[6];
  const float* b_hh   = (const float*)d_in[7];
  const float* W1     = (const float*)d_in[8];
  const float* b1     = (const float*)d_in[9];
  const float* W2     = (const float*)d_in[10];
  const float* b2     = (const float*)d_in[11];
  float* out = (float*)d_out;

  _Float16* wsh  = (_Float16*)d_ws;
  _Float16* W1h  = wsh;             // 65536
  _Float16* W2h  = wsh + 65536;     // 65536
  _Float16* Wihh = wsh + 131072;    // 131072
  _Float16* Whhh = wsh + 262144;    // 262144  (total 1 MB)

  cvt_f32_f16<<<64,  256, 0, stream>>>(W1,   W1h,  16384);
  cvt_f32_f16<<<64,  256, 0, stream>>>(W2,   W2h,  16384);
  cvt_f32_f16<<<128, 256, 0, stream>>>(W_ih, Wihh, 32768);
  cvt_f32_f16<<<256, 256, 0, stream>>>(W_hh, Whhh, 65536);

  ode_lstm<<<B_TOT/BT, 512, 0, stream>>>(inputs, h0, c0, ts, b_ih, b_hh, b1, b2,
                                         W1h, W2h, Wihh, Whhh, out);
}